// Round 15
// baseline (217.908 us; speedup 1.0000x reference)
//
#include <hip/hip_runtime.h>
#include <hip/hip_fp16.h>

#define CCH 64      // channels
#define BKT 256     // rows per bucket -> NB = 196
#define NBMAX 200
#define CAP 6144    // bdata bucket capacity (mean 5120, sigma 71: +14 sigma, R11-proven)
#define SCAP 6912   // sdat bucket capacity, 8-aligned (padded mean 6016, +12 sigma)
#define PCH 8192    // edges per partition chunk
#define GR 64       // rows per gemm chunk

typedef int int4a __attribute__((ext_vector_type(4), aligned(4)));

__device__ __forceinline__ int scan256ex(int v, int t, int* wsum) {
    // exclusive prefix over 256 threads (R10/R11-verified)
    int s = v;
    #pragma unroll
    for (int off = 1; off < 64; off <<= 1) {
        int u = __shfl_up(s, off, 64);
        if ((t & 63) >= off) s += u;
    }
    if ((t & 63) == 63) wsum[t >> 6] = s;
    __syncthreads();
    int wpre = 0;
    #pragma unroll
    for (int j = 0; j < 4; ++j) if (j < (t >> 6)) wpre += wsum[j];
    return wpre + s - v;
}

// ---- k_part (R14-measured good): atomic run reservation + bucket-ordered LDS
//      staging with COALESCED copy-out. ----
__global__ void __launch_bounds__(256) k_part(const int* __restrict__ e0,
        const int* __restrict__ e1, const int* __restrict__ e2,
        int* __restrict__ bucketcur, unsigned* __restrict__ bdata,
        int E, int NB) {
    int c = blockIdx.y;
    const int* ed = (c == 0) ? e0 : (c == 1) ? e1 : e2;
    int base = blockIdx.x * PCH;
    int nE = E - base; if (nE > PCH) nE = PCH;
    __shared__ unsigned staged[PCH];    // 32 KB, bucket-ordered
    __shared__ int hist[NBMAX];
    __shared__ int off[NBMAX];
    __shared__ int wsum[4];
    int t = threadIdx.x;
    if (t < NB) hist[t] = 0;
    __syncthreads();
    const int* dd = ed + E;
    for (int k = t * 4; k < nE; k += 1024) {
        if (k + 3 < nE) {
            int4a d = *(const int4a*)(dd + base + k);
            atomicAdd(&hist[d.x >> 8], 1); atomicAdd(&hist[d.y >> 8], 1);
            atomicAdd(&hist[d.z >> 8], 1); atomicAdd(&hist[d.w >> 8], 1);
        } else {
            for (int j = k; j < nE; ++j) atomicAdd(&hist[dd[base + j] >> 8], 1);
        }
    }
    __syncthreads();
    int v = (t < NB) ? hist[t] : 0;
    int lbase = scan256ex(v, t, wsum);
    if (t < NB) {
        int old = atomicAdd(&bucketcur[c * NB + t], v);
        off[t] = t * CAP + old - lbase;
    }
    __syncthreads();
    if (t < NB) hist[t] = lbase;
    __syncthreads();
    for (int k = t * 4; k < nE; k += 1024) {
        if (k + 3 < nE) {
            int4a s4 = *(const int4a*)(ed + base + k);
            int4a d4 = *(const int4a*)(ed + E + base + k);
            int sl;
            sl = atomicAdd(&hist[d4.x >> 8], 1); staged[sl] = (unsigned)s4.x | ((unsigned)d4.x << 16);
            sl = atomicAdd(&hist[d4.y >> 8], 1); staged[sl] = (unsigned)s4.y | ((unsigned)d4.y << 16);
            sl = atomicAdd(&hist[d4.z >> 8], 1); staged[sl] = (unsigned)s4.z | ((unsigned)d4.z << 16);
            sl = atomicAdd(&hist[d4.w >> 8], 1); staged[sl] = (unsigned)s4.w | ((unsigned)d4.w << 16);
        } else {
            for (int j = k; j < nE; ++j) {
                int s0 = ed[base + j];
                int d0 = ed[E + base + j];
                int sl = atomicAdd(&hist[d0 >> 8], 1);
                staged[sl] = (unsigned)s0 | ((unsigned)d0 << 16);
            }
        }
    }
    __syncthreads();
    unsigned* bo = bdata + (size_t)c * NB * CAP;
    for (int sI = t; sI < nE; sI += 256) {
        unsigned rec = staged[sI];
        int b = (int)(rec >> 24);
        bo[off[b] + sI] = rec;
    }
}

// ---- k_sort (R15): per-bucket counting sort with 8-PADDED row lists.
//      Row lists are padded to multiples of 8 with dummy index N (the all-zero
//      h16 row) so k_pull's loop is fully unpredicated, no masked tail. ----
__global__ void __launch_bounds__(256) k_sort(const unsigned* __restrict__ bdata,
        const int* __restrict__ bucketcur, int* __restrict__ sdat,
        int* __restrict__ rst, int* __restrict__ ren, float* __restrict__ dinv,
        int N, int NB) {
    int c = blockIdx.y, b = blockIdx.x;
    __shared__ unsigned staged[CAP];    // 24 KB
    __shared__ unsigned sorted[SCAP];   // 27 KB
    __shared__ int cnt[BKT];
    __shared__ int cur[BKT];
    __shared__ int wsum[4];
    __shared__ int sh_tot;
    int t = threadIdx.x;
    cnt[t] = 0;
    __syncthreads();
    int n = bucketcur[c * NB + b]; if (n > CAP) n = CAP;
    size_t g0 = (size_t)c * NB * CAP + (size_t)b * CAP;
    for (int i = t; i < n; i += 256) staged[i] = bdata[g0 + i];
    __syncthreads();
    for (int i = t; i < n; i += 256)
        atomicAdd(&cnt[(staged[i] >> 16) & 255], 1);
    __syncthreads();
    int v = cnt[t];
    int pl = (v + 7) & ~7;              // padded row length
    int pex = scan256ex(pl, t, wsum);   // padded exclusive prefix (8-aligned)
    cur[t] = pex;
    int row = b * BKT + t;
    if (row < N) {
        rst[c * N + row] = b * SCAP + pex;
        ren[c * N + row] = b * SCAP + pex + pl;
        dinv[(size_t)c * N + row] = rsqrtf((float)(v + 1));
    }
    if (t == 255) sh_tot = pex + pl;
    __syncthreads();
    int ptot = sh_tot;                  // <= SCAP by construction
    for (int i = t; i < ptot; i += 256) sorted[i] = (unsigned)N;  // pad fill
    __syncthreads();
    for (int i = t; i < n; i += 256) {
        unsigned r = staged[i];
        int slot = atomicAdd(&cur[(r >> 16) & 255], 1);
        sorted[slot] = r & 0xFFFFu;
    }
    __syncthreads();
    int* so = sdat + (size_t)c * NB * SCAP + (size_t)b * SCAP;
    for (int i = t; i < ptot; i += 256) so[i] = (int)sorted[i];
}

// ---- h16[c,row,:] = fp16( (x_row . W_c) * dinv[c,row] ), register-tiled,
//      N+1 rows per conv: row N is the all-zero pad target (block 0 zeroes it).
//      Star path computes BOTH conv0 and conv1 from ONE x_star read. ----
__global__ void __launch_bounds__(256) k_gemm_all(const float* __restrict__ xs_,
        const float* __restrict__ xg_, const float* __restrict__ W0,
        const float* __restrict__ W1, const float* __restrict__ W2,
        const float* __restrict__ dinv, __half* __restrict__ h16, int N) {
    int star = (blockIdx.y == 0);
    const float* x = star ? xs_ : xg_;
    __shared__ float Ws[2][CCH * CCH];    // 32 KB (gal uses [0] only)
    __shared__ float xT[CCH * (GR + 1)];  // [k][row], stride 65
    int t = threadIdx.x;
    int row0 = blockIdx.x * GR;
    size_t NC = (size_t)(N + 1) * CCH;    // N+1 rows per conv
    if (blockIdx.x == 0) {                // zero the pad row (row N)
        if (star) {
            if (t < 32) ((float*)(h16 + (size_t)N * CCH))[t] = 0.f;
            else if (t < 64) ((float*)(h16 + NC + (size_t)N * CCH))[t - 32] = 0.f;
        } else {
            if (t < 32) ((float*)(h16 + 2 * NC + (size_t)N * CCH))[t] = 0.f;
        }
    }
    if (star) {
        #pragma unroll
        for (int j = 0; j < 4; ++j) {
            int idx = j * 1024 + t * 4;
            *(float4*)(&Ws[0][idx]) = *(const float4*)(W0 + idx);
            *(float4*)(&Ws[1][idx]) = *(const float4*)(W1 + idx);
        }
    } else {
        #pragma unroll
        for (int j = 0; j < 4; ++j) {
            int idx = j * 1024 + t * 4;
            *(float4*)(&Ws[0][idx]) = *(const float4*)(W2 + idx);
        }
    }
    #pragma unroll
    for (int j = 0; j < 4; ++j) {
        int idx = t + j * 256;
        int r = idx >> 4;
        int c0 = (idx & 15) * 4;
        int row = row0 + r;
        float4 v = make_float4(0.f, 0.f, 0.f, 0.f);
        if (row < N) v = *(const float4*)(x + (size_t)row * CCH + c0);
        xT[(c0 + 0) * (GR + 1) + r] = v.x;
        xT[(c0 + 1) * (GR + 1) + r] = v.y;
        xT[(c0 + 2) * (GR + 1) + r] = v.z;
        xT[(c0 + 3) * (GR + 1) + r] = v.w;
    }
    __syncthreads();
    int c4 = (t & 15) * 4;
    int r0 = (t >> 4) * 4;
    if (star) {
        float4 a0 = make_float4(0.f, 0.f, 0.f, 0.f), a1 = a0, a2 = a0, a3 = a0;
        float4 d0 = a0, d1 = a0, d2 = a0, d3 = a0;
        #pragma unroll 4
        for (int k = 0; k < CCH; ++k) {
            float4 wv = *(float4*)(&Ws[0][k * CCH + c4]);
            float4 uv = *(float4*)(&Ws[1][k * CCH + c4]);
            float x0 = xT[k * (GR + 1) + r0 + 0];
            float x1 = xT[k * (GR + 1) + r0 + 1];
            float x2 = xT[k * (GR + 1) + r0 + 2];
            float x3 = xT[k * (GR + 1) + r0 + 3];
            a0.x += x0 * wv.x; a0.y += x0 * wv.y; a0.z += x0 * wv.z; a0.w += x0 * wv.w;
            a1.x += x1 * wv.x; a1.y += x1 * wv.y; a1.z += x1 * wv.z; a1.w += x1 * wv.w;
            a2.x += x2 * wv.x; a2.y += x2 * wv.y; a2.z += x2 * wv.z; a2.w += x2 * wv.w;
            a3.x += x3 * wv.x; a3.y += x3 * wv.y; a3.z += x3 * wv.z; a3.w += x3 * wv.w;
            d0.x += x0 * uv.x; d0.y += x0 * uv.y; d0.z += x0 * uv.z; d0.w += x0 * uv.w;
            d1.x += x1 * uv.x; d1.y += x1 * uv.y; d1.z += x1 * uv.z; d1.w += x1 * uv.w;
            d2.x += x2 * uv.x; d2.y += x2 * uv.y; d2.z += x2 * uv.z; d2.w += x2 * uv.w;
            d3.x += x3 * uv.x; d3.y += x3 * uv.y; d3.z += x3 * uv.z; d3.w += x3 * uv.w;
        }
        float4 av[4] = {a0, a1, a2, a3};
        float4 dv4[4] = {d0, d1, d2, d3};
        #pragma unroll
        for (int i = 0; i < 4; ++i) {
            int row = row0 + r0 + i;
            if (row < N) {
                float dd0 = dinv[row];
                float dd1 = dinv[N + row];
                union { __half2 h2[2]; float2 f2; } u;
                u.h2[0] = __floats2half2_rn(av[i].x * dd0, av[i].y * dd0);
                u.h2[1] = __floats2half2_rn(av[i].z * dd0, av[i].w * dd0);
                *(float2*)(h16 + (size_t)row * CCH + c4) = u.f2;
                u.h2[0] = __floats2half2_rn(dv4[i].x * dd1, dv4[i].y * dd1);
                u.h2[1] = __floats2half2_rn(dv4[i].z * dd1, dv4[i].w * dd1);
                *(float2*)(h16 + NC + (size_t)row * CCH + c4) = u.f2;
            }
        }
    } else {
        float4 a0 = make_float4(0.f, 0.f, 0.f, 0.f), a1 = a0, a2 = a0, a3 = a0;
        #pragma unroll 8
        for (int k = 0; k < CCH; ++k) {
            float4 wv = *(float4*)(&Ws[0][k * CCH + c4]);
            float x0 = xT[k * (GR + 1) + r0 + 0];
            float x1 = xT[k * (GR + 1) + r0 + 1];
            float x2 = xT[k * (GR + 1) + r0 + 2];
            float x3 = xT[k * (GR + 1) + r0 + 3];
            a0.x += x0 * wv.x; a0.y += x0 * wv.y; a0.z += x0 * wv.z; a0.w += x0 * wv.w;
            a1.x += x1 * wv.x; a1.y += x1 * wv.y; a1.z += x1 * wv.z; a1.w += x1 * wv.w;
            a2.x += x2 * wv.x; a2.y += x2 * wv.y; a2.z += x2 * wv.z; a2.w += x2 * wv.w;
            a3.x += x3 * wv.x; a3.y += x3 * wv.y; a3.z += x3 * wv.z; a3.w += x3 * wv.w;
        }
        float4 av[4] = {a0, a1, a2, a3};
        #pragma unroll
        for (int i = 0; i < 4; ++i) {
            int row = row0 + r0 + i;
            if (row < N) {
                float dd = dinv[2 * N + row];
                union { __half2 h2[2]; float2 f2; } u;
                u.h2[0] = __floats2half2_rn(av[i].x * dd, av[i].y * dd);
                u.h2[1] = __floats2half2_rn(av[i].z * dd, av[i].w * dd);
                *(float2*)(h16 + 2 * NC + (size_t)row * CCH + c4) = u.f2;
            }
        }
    }
}

// ---- gather 4 fp16 channels (8B dwordx2) from a row pointer ----
__device__ __forceinline__ float4 gat4p(const __half* __restrict__ p, int l16) {
    union { float2 f2; __half2 h2[2]; } u;
    u.f2 = ((const float2*)p)[l16];
    float2 a = __half22float2(u.h2[0]);
    float2 b = __half22float2(u.h2[1]);
    return make_float4(a.x, a.y, b.x, b.y);
}

__device__ __forceinline__ void acc4(float4& a, float4 v) {
    a.x += v.x; a.y += v.y; a.z += v.z; a.w += v.w;
}

// ---- fused pull (R15): row lists are 8-padded (pads point at zero row N) so
//      the loop is FULLY UNPREDICATED — no masked tail, no zrow selects.
//      Quarter splits are in 8-blocks (exact). Star/gal split via row0. ----
__global__ void __launch_bounds__(256) k_pull(const int* __restrict__ rst,
        const int* __restrict__ ren,
        const int* __restrict__ sdat, const __half* __restrict__ h16,
        const float* __restrict__ dinv,
        const float* __restrict__ b0, const float* __restrict__ b1,
        const float* __restrict__ b2,
        float* __restrict__ out, int N, int GAPE, int row0) {
    int row = row0 + blockIdx.x * 4 + (threadIdx.x >> 6);
    if (row >= 2 * N) return;
    int lane = threadIdx.x & 63;
    int q = lane >> 4;          // quarter 0..3
    int l16 = lane & 15;
    size_t NC = (size_t)(N + 1) * CCH;  // N+1 rows per conv (row N = zeros)
    size_t NOUT = (size_t)N * CCH;

    const __half* hcL;
    const int* sdL;
    int beg, end;
    float ddL;
    float4 bias;
    float* op;
    float4 acc = make_float4(0.f, 0.f, 0.f, 0.f);
    if (row < N) {                          // star: q0,q1=conv0; q2,q3=conv1
        int cv = q >> 1;
        int bg = rst[cv * N + row], eg = ren[cv * N + row];
        int nb = (eg - bg) >> 3;            // 8-blocks in padded list
        int h1 = (nb + 1) >> 1;
        beg = (q & 1) ? bg + 8 * h1 : bg;
        end = (q & 1) ? eg : bg + 8 * h1;
        hcL = h16 + (size_t)cv * NC;
        sdL = sdat + (size_t)cv * GAPE;
        ddL = dinv[cv * N + row];
        if (!(q & 1)) acc = gat4p(hcL + (size_t)row * CCH, l16); // self-loop
        float4 bv0 = ((const float4*)b0)[l16];
        float4 bv1 = ((const float4*)b1)[l16];
        bias = make_float4(bv0.x + bv1.x, bv0.y + bv1.y,
                           bv0.z + bv1.z, bv0.w + bv1.w);
        op = out + (size_t)row * CCH;
    } else {                                // gal: 4 segments of one list
        int r = row - N;
        int bg = rst[2 * N + r], eg = ren[2 * N + r];
        int nb = (eg - bg) >> 3;
        beg = bg + 8 * ((nb * q) >> 2);
        end = bg + 8 * ((nb * (q + 1)) >> 2);
        hcL = h16 + 2 * NC;
        sdL = sdat + 2 * (size_t)GAPE;
        ddL = dinv[2 * N + r];
        if (q == 0) acc = gat4p(hcL + (size_t)r * CCH, l16);
        bias = ((const float4*)b2)[l16];
        op = out + NOUT + (size_t)r * CCH;
    }

    for (int i = beg; i < end; i += 8) {    // fully unpredicated
        int4a q0 = *(const int4a*)(sdL + i);
        int4a q1 = *(const int4a*)(sdL + i + 4);
        float4 v0 = gat4p(hcL + (size_t)q0.x * CCH, l16);
        float4 v1 = gat4p(hcL + (size_t)q0.y * CCH, l16);
        float4 v2 = gat4p(hcL + (size_t)q0.z * CCH, l16);
        float4 v3 = gat4p(hcL + (size_t)q0.w * CCH, l16);
        float4 v4 = gat4p(hcL + (size_t)q1.x * CCH, l16);
        float4 v5 = gat4p(hcL + (size_t)q1.y * CCH, l16);
        float4 v6 = gat4p(hcL + (size_t)q1.z * CCH, l16);
        float4 v7 = gat4p(hcL + (size_t)q1.w * CCH, l16);
        acc4(acc, v0); acc4(acc, v1); acc4(acc, v2); acc4(acc, v3);
        acc4(acc, v4); acc4(acc, v5); acc4(acc, v6); acc4(acc, v7);
    }

    float4 t;
    t.x = acc.x * ddL; t.y = acc.y * ddL; t.z = acc.z * ddL; t.w = acc.w * ddL;
    t.x += __shfl_xor(t.x, 16, 64); t.y += __shfl_xor(t.y, 16, 64);
    t.z += __shfl_xor(t.z, 16, 64); t.w += __shfl_xor(t.w, 16, 64);
    t.x += __shfl_xor(t.x, 32, 64); t.y += __shfl_xor(t.y, 32, 64);
    t.z += __shfl_xor(t.z, 32, 64); t.w += __shfl_xor(t.w, 32, 64);
    if (lane < 16) {
        t.x += bias.x; t.y += bias.y; t.z += bias.z; t.w += bias.w;
        ((float4*)op)[l16] = t;
    }
}

static inline size_t align256(size_t x) { return (x + 255) & ~(size_t)255; }

extern "C" void kernel_launch(void* const* d_in, const int* in_sizes, int n_in,
                              void* d_out, int out_size, void* d_ws, size_t ws_size,
                              hipStream_t stream) {
    const float* x_star = (const float*)d_in[0];
    const float* x_gal  = (const float*)d_in[1];
    const int*   e_ssn  = (const int*)d_in[2];
    const int*   e_ssf  = (const int*)d_in[3];
    const int*   e_ggn  = (const int*)d_in[4];
    const float* W_ssn  = (const float*)d_in[5];
    const float* W_ssf  = (const float*)d_in[6];
    const float* W_ggn  = (const float*)d_in[7];
    const float* b_ssn  = (const float*)d_in[8];
    const float* b_ssf  = (const float*)d_in[9];
    const float* b_ggn  = (const float*)d_in[10];

    const int N  = in_sizes[0] / CCH;       // 50000
    const int E  = in_sizes[2] / 2;         // 1000000
    const size_t NC1 = (size_t)(N + 1) * CCH;
    const int NB   = (N + BKT - 1) / BKT;   // 196 buckets per conv
    const int NBLK = (E + PCH - 1) / PCH;   // 123 partition chunks per conv
    const int GAPE = NB * SCAP;             // padded per-conv sdat region

    // workspace layout
    char* w = (char*)d_ws;
    __half*   h16    = (__half*)w;   w += align256((size_t)3 * NC1 * 2);
    float*    dinv   = (float*)w;    w += align256((size_t)3 * N * 4);
    unsigned* bdata  = (unsigned*)w; w += align256((size_t)3 * NB * CAP * 4);
    int*      sdat   = (int*)w;      w += align256((size_t)3 * GAPE * 4);
    int*      bucketcur = (int*)w;   w += align256((size_t)3 * NB * 4);
    int*      rst    = (int*)w;      w += align256((size_t)3 * N * 4);
    int*      ren    = (int*)w;      w += align256((size_t)3 * N * 4);

    const int B = 256;

    hipMemsetAsync(bucketcur, 0, (size_t)3 * NB * 4, stream);
    k_part<<<dim3(NBLK, 3), B, 0, stream>>>(e_ssn, e_ssf, e_ggn,
                                            bucketcur, bdata, E, NB);
    k_sort<<<dim3(NB, 3), B, 0, stream>>>(bdata, bucketcur, sdat,
                                          rst, ren, dinv, N, NB);
    k_gemm_all<<<dim3((N + GR - 1) / GR, 2), B, 0, stream>>>(x_star, x_gal,
                                                             W_ssn, W_ssf, W_ggn,
                                                             dinv, h16, N);
    k_pull<<<(N + 3) / 4, B, 0, stream>>>(rst, ren, sdat, h16, dinv,
                                          b_ssn, b_ssf, b_ggn,
                                          (float*)d_out, N, GAPE, 0);
    k_pull<<<(N + 3) / 4, B, 0, stream>>>(rst, ren, sdat, h16, dinv,
                                          b_ssn, b_ssf, b_ggn,
                                          (float*)d_out, N, GAPE, N);
}

// Round 16
// 204.946 us; speedup vs baseline: 1.0632x; 1.0632x over previous
//
#include <hip/hip_runtime.h>
#include <hip/hip_fp16.h>

#define CCH 64      // channels
#define BKT 256     // rows per bucket -> NB = 196
#define NBMAX 200
#define CAP 6144    // bucket region capacity (mean 5120, sigma 71: +14 sigma)
#define PCH 8192    // edges per partition chunk
#define GR 64       // rows per gemm chunk

typedef int int4a __attribute__((ext_vector_type(4), aligned(4)));

__device__ __forceinline__ int scan256ex(int v, int t, int* wsum) {
    // exclusive prefix over 256 threads (R10/R11-verified)
    int s = v;
    #pragma unroll
    for (int off = 1; off < 64; off <<= 1) {
        int u = __shfl_up(s, off, 64);
        if ((t & 63) >= off) s += u;
    }
    if ((t & 63) == 63) wsum[t >> 6] = s;
    __syncthreads();
    int wpre = 0;
    #pragma unroll
    for (int j = 0; j < 4; ++j) if (j < (t >> 6)) wpre += wsum[j];
    return wpre + s - v;
}

// ---- k_part (R14-measured good): atomic run reservation (R11) + bucket-ordered
//      LDS staging with COALESCED copy-out (R5-verified write pattern). Pass1
//      counts dst; pass2 re-reads edges (L2-hot) into bucket-ordered LDS;
//      copy-out runs (avg 42 recs) are near-linear. ----
__global__ void __launch_bounds__(256) k_part(const int* __restrict__ e0,
        const int* __restrict__ e1, const int* __restrict__ e2,
        int* __restrict__ bucketcur, unsigned* __restrict__ bdata,
        int E, int NB) {
    int c = blockIdx.y;
    const int* ed = (c == 0) ? e0 : (c == 1) ? e1 : e2;
    int base = blockIdx.x * PCH;
    int nE = E - base; if (nE > PCH) nE = PCH;
    __shared__ unsigned staged[PCH];    // 32 KB, bucket-ordered
    __shared__ int hist[NBMAX];         // counts -> staging cursors
    __shared__ int off[NBMAX];          // global run base minus local base
    __shared__ int wsum[4];
    int t = threadIdx.x;
    if (t < NB) hist[t] = 0;
    __syncthreads();
    const int* dd = ed + E;
    // pass 1: histogram of dst (12 MB read, vectorized)
    for (int k = t * 4; k < nE; k += 1024) {
        if (k + 3 < nE) {
            int4a d = *(const int4a*)(dd + base + k);
            atomicAdd(&hist[d.x >> 8], 1); atomicAdd(&hist[d.y >> 8], 1);
            atomicAdd(&hist[d.z >> 8], 1); atomicAdd(&hist[d.w >> 8], 1);
        } else {
            for (int j = k; j < nE; ++j) atomicAdd(&hist[dd[base + j] >> 8], 1);
        }
    }
    __syncthreads();
    // reserve global runs + local exclusive prefix
    int v = (t < NB) ? hist[t] : 0;
    int lbase = scan256ex(v, t, wsum);      // local staging base
    if (t < NB) {
        int old = atomicAdd(&bucketcur[c * NB + t], v);
        off[t] = t * CAP + old - lbase;     // global = off[b] + local index
    }
    __syncthreads();
    if (t < NB) hist[t] = lbase;            // staging cursor
    __syncthreads();
    // pass 2: re-read edges (L2-hot), scatter into bucket-ordered LDS
    for (int k = t * 4; k < nE; k += 1024) {
        if (k + 3 < nE) {
            int4a s4 = *(const int4a*)(ed + base + k);
            int4a d4 = *(const int4a*)(ed + E + base + k);
            int sl;
            sl = atomicAdd(&hist[d4.x >> 8], 1); staged[sl] = (unsigned)s4.x | ((unsigned)d4.x << 16);
            sl = atomicAdd(&hist[d4.y >> 8], 1); staged[sl] = (unsigned)s4.y | ((unsigned)d4.y << 16);
            sl = atomicAdd(&hist[d4.z >> 8], 1); staged[sl] = (unsigned)s4.z | ((unsigned)d4.z << 16);
            sl = atomicAdd(&hist[d4.w >> 8], 1); staged[sl] = (unsigned)s4.w | ((unsigned)d4.w << 16);
        } else {
            for (int j = k; j < nE; ++j) {
                int s0 = ed[base + j];
                int d0 = ed[E + base + j];
                int sl = atomicAdd(&hist[d0 >> 8], 1);
                staged[sl] = (unsigned)s0 | ((unsigned)d0 << 16);
            }
        }
    }
    __syncthreads();
    // copy-out: consecutive sI within a bucket run -> consecutive global addrs
    unsigned* bo = bdata + (size_t)c * NB * CAP;
    for (int sI = t; sI < nE; sI += 256) {
        unsigned rec = staged[sI];
        int b = (int)(rec >> 24);           // dst>>8
        bo[off[b] + sI] = rec;
    }
}

// ---- k_sort (R11-verified, in both 211.7 and 205.3 totals): per-bucket
//      counting sort; scatter lands in LDS sorted[] and the global write is a
//      LINEAR coalesced copy (R13 proved direct global scatter costs +12 us). ----
__global__ void __launch_bounds__(256) k_sort(const unsigned* __restrict__ bdata,
        const int* __restrict__ bucketcur, int* __restrict__ sdat,
        int* __restrict__ rst, int* __restrict__ ren, float* __restrict__ dinv,
        __half* __restrict__ zrow, int N, int NB) {
    int c = blockIdx.y, b = blockIdx.x;
    __shared__ unsigned staged[CAP];    // 24.6 KB
    __shared__ unsigned sorted[CAP];    // 24.6 KB
    __shared__ int cnt[BKT];
    __shared__ int cur[BKT];
    __shared__ int wsum[4];
    int t = threadIdx.x;
    if (c == 0 && b == 0 && t < 32) ((float*)zrow)[t] = 0.f;
    cnt[t] = 0;
    __syncthreads();
    int n = bucketcur[c * NB + b]; if (n > CAP) n = CAP;
    size_t g0 = (size_t)c * NB * CAP + (size_t)b * CAP;
    for (int i = t; i < n; i += 256) staged[i] = bdata[g0 + i];
    __syncthreads();
    for (int i = t; i < n; i += 256)
        atomicAdd(&cnt[(staged[i] >> 16) & 255], 1);
    __syncthreads();
    int v = cnt[t];
    int ex = scan256ex(v, t, wsum);
    cur[t] = ex;
    int row = b * BKT + t;
    if (row < N) {
        rst[c * N + row] = b * CAP + ex;
        ren[c * N + row] = b * CAP + ex + v;
        dinv[(size_t)c * N + row] = rsqrtf((float)(v + 1));
    }
    __syncthreads();
    for (int i = t; i < n; i += 256) {
        unsigned r = staged[i];
        int slot = atomicAdd(&cur[(r >> 16) & 255], 1);
        sorted[slot] = r & 0xFFFFu;
    }
    __syncthreads();
    int* so = sdat + (size_t)c * NB * CAP;
    for (int i = t; i < n; i += 256) so[(size_t)b * CAP + i] = (int)sorted[i];
}

// ---- h16[c,row,:] = fp16( (x_row . W_c) * dinv[c,row] ), register-tiled.
//      Star path computes BOTH conv0 and conv1 from ONE x_star read. ----
__global__ void __launch_bounds__(256) k_gemm_all(const float* __restrict__ xs_,
        const float* __restrict__ xg_, const float* __restrict__ W0,
        const float* __restrict__ W1, const float* __restrict__ W2,
        const float* __restrict__ dinv, __half* __restrict__ h16, int N) {
    int star = (blockIdx.y == 0);
    const float* x = star ? xs_ : xg_;
    __shared__ float Ws[2][CCH * CCH];    // 32 KB (gal uses [0] only)
    __shared__ float xT[CCH * (GR + 1)];  // [k][row], stride 65
    int t = threadIdx.x;
    int row0 = blockIdx.x * GR;
    size_t NC = (size_t)N * CCH;
    if (star) {
        #pragma unroll
        for (int j = 0; j < 4; ++j) {
            int idx = j * 1024 + t * 4;
            *(float4*)(&Ws[0][idx]) = *(const float4*)(W0 + idx);
            *(float4*)(&Ws[1][idx]) = *(const float4*)(W1 + idx);
        }
    } else {
        #pragma unroll
        for (int j = 0; j < 4; ++j) {
            int idx = j * 1024 + t * 4;
            *(float4*)(&Ws[0][idx]) = *(const float4*)(W2 + idx);
        }
    }
    #pragma unroll
    for (int j = 0; j < 4; ++j) {
        int idx = t + j * 256;
        int r = idx >> 4;
        int c0 = (idx & 15) * 4;
        int row = row0 + r;
        float4 v = make_float4(0.f, 0.f, 0.f, 0.f);
        if (row < N) v = *(const float4*)(x + (size_t)row * CCH + c0);
        xT[(c0 + 0) * (GR + 1) + r] = v.x;
        xT[(c0 + 1) * (GR + 1) + r] = v.y;
        xT[(c0 + 2) * (GR + 1) + r] = v.z;
        xT[(c0 + 3) * (GR + 1) + r] = v.w;
    }
    __syncthreads();
    int c4 = (t & 15) * 4;
    int r0 = (t >> 4) * 4;
    if (star) {
        float4 a0 = make_float4(0.f, 0.f, 0.f, 0.f), a1 = a0, a2 = a0, a3 = a0;
        float4 d0 = a0, d1 = a0, d2 = a0, d3 = a0;
        #pragma unroll 4
        for (int k = 0; k < CCH; ++k) {
            float4 wv = *(float4*)(&Ws[0][k * CCH + c4]);
            float4 uv = *(float4*)(&Ws[1][k * CCH + c4]);
            float x0 = xT[k * (GR + 1) + r0 + 0];
            float x1 = xT[k * (GR + 1) + r0 + 1];
            float x2 = xT[k * (GR + 1) + r0 + 2];
            float x3 = xT[k * (GR + 1) + r0 + 3];
            a0.x += x0 * wv.x; a0.y += x0 * wv.y; a0.z += x0 * wv.z; a0.w += x0 * wv.w;
            a1.x += x1 * wv.x; a1.y += x1 * wv.y; a1.z += x1 * wv.z; a1.w += x1 * wv.w;
            a2.x += x2 * wv.x; a2.y += x2 * wv.y; a2.z += x2 * wv.z; a2.w += x2 * wv.w;
            a3.x += x3 * wv.x; a3.y += x3 * wv.y; a3.z += x3 * wv.z; a3.w += x3 * wv.w;
            d0.x += x0 * uv.x; d0.y += x0 * uv.y; d0.z += x0 * uv.z; d0.w += x0 * uv.w;
            d1.x += x1 * uv.x; d1.y += x1 * uv.y; d1.z += x1 * uv.z; d1.w += x1 * uv.w;
            d2.x += x2 * uv.x; d2.y += x2 * uv.y; d2.z += x2 * uv.z; d2.w += x2 * uv.w;
            d3.x += x3 * uv.x; d3.y += x3 * uv.y; d3.z += x3 * uv.z; d3.w += x3 * uv.w;
        }
        float4 av[4] = {a0, a1, a2, a3};
        float4 dv4[4] = {d0, d1, d2, d3};
        #pragma unroll
        for (int i = 0; i < 4; ++i) {
            int row = row0 + r0 + i;
            if (row < N) {
                float dd0 = dinv[row];
                float dd1 = dinv[N + row];
                union { __half2 h2[2]; float2 f2; } u;
                u.h2[0] = __floats2half2_rn(av[i].x * dd0, av[i].y * dd0);
                u.h2[1] = __floats2half2_rn(av[i].z * dd0, av[i].w * dd0);
                *(float2*)(h16 + (size_t)row * CCH + c4) = u.f2;
                u.h2[0] = __floats2half2_rn(dv4[i].x * dd1, dv4[i].y * dd1);
                u.h2[1] = __floats2half2_rn(dv4[i].z * dd1, dv4[i].w * dd1);
                *(float2*)(h16 + NC + (size_t)row * CCH + c4) = u.f2;
            }
        }
    } else {
        float4 a0 = make_float4(0.f, 0.f, 0.f, 0.f), a1 = a0, a2 = a0, a3 = a0;
        #pragma unroll 8
        for (int k = 0; k < CCH; ++k) {
            float4 wv = *(float4*)(&Ws[0][k * CCH + c4]);
            float x0 = xT[k * (GR + 1) + r0 + 0];
            float x1 = xT[k * (GR + 1) + r0 + 1];
            float x2 = xT[k * (GR + 1) + r0 + 2];
            float x3 = xT[k * (GR + 1) + r0 + 3];
            a0.x += x0 * wv.x; a0.y += x0 * wv.y; a0.z += x0 * wv.z; a0.w += x0 * wv.w;
            a1.x += x1 * wv.x; a1.y += x1 * wv.y; a1.z += x1 * wv.z; a1.w += x1 * wv.w;
            a2.x += x2 * wv.x; a2.y += x2 * wv.y; a2.z += x2 * wv.z; a2.w += x2 * wv.w;
            a3.x += x3 * wv.x; a3.y += x3 * wv.y; a3.z += x3 * wv.z; a3.w += x3 * wv.w;
        }
        float4 av[4] = {a0, a1, a2, a3};
        #pragma unroll
        for (int i = 0; i < 4; ++i) {
            int row = row0 + r0 + i;
            if (row < N) {
                float dd = dinv[2 * N + row];
                union { __half2 h2[2]; float2 f2; } u;
                u.h2[0] = __floats2half2_rn(av[i].x * dd, av[i].y * dd);
                u.h2[1] = __floats2half2_rn(av[i].z * dd, av[i].w * dd);
                *(float2*)(h16 + 2 * NC + (size_t)row * CCH + c4) = u.f2;
            }
        }
    }
}

// ---- gather 4 fp16 channels (8B dwordx2) from a row pointer ----
__device__ __forceinline__ float4 gat4p(const __half* __restrict__ p, int l16) {
    union { float2 f2; __half2 h2[2]; } u;
    u.f2 = ((const float2*)p)[l16];
    float2 a = __half22float2(u.h2[0]);
    float2 b = __half22float2(u.h2[1]);
    return make_float4(a.x, a.y, b.x, b.y);
}

__device__ __forceinline__ void acc4(float4& a, float4 v) {
    a.x += v.x; a.y += v.y; a.z += v.z; a.w += v.w;
}

// ---- fused pull (R11/R14-measured 63.9 us), gapped layout. Random-gather
//      bound: ~390 MB gather demand served at ~6.2 TB/s aggregate L2+HBM —
//      structural floor (R2/R15 restructurings both null). ----
__global__ void __launch_bounds__(256) k_pull(const int* __restrict__ rst,
        const int* __restrict__ ren,
        const int* __restrict__ sdat, const __half* __restrict__ h16,
        const float* __restrict__ dinv, const __half* __restrict__ zrow,
        const float* __restrict__ b0, const float* __restrict__ b1,
        const float* __restrict__ b2,
        float* __restrict__ out, int N, int GAPE) {
    int row = blockIdx.x * 4 + (threadIdx.x >> 6);
    if (row >= 2 * N) return;
    int lane = threadIdx.x & 63;
    int q = lane >> 4;          // quarter 0..3
    int l16 = lane & 15;
    size_t NC = (size_t)N * CCH;

    const __half* hcL;
    const int* sdL;
    int beg, end;
    float ddL;
    float4 bias;
    float* op;
    float4 acc = make_float4(0.f, 0.f, 0.f, 0.f);
    if (row < N) {                          // star: q0,q1=conv0; q2,q3=conv1
        int cv = q >> 1;
        int bg = rst[cv * N + row], eg = ren[cv * N + row];
        int mid = (bg + eg) >> 1;
        beg = (q & 1) ? mid : bg;
        end = (q & 1) ? eg : mid;
        hcL = h16 + (size_t)cv * NC;
        sdL = sdat + (size_t)cv * GAPE;
        ddL = dinv[cv * N + row];
        if (!(q & 1)) acc = gat4p(hcL + (size_t)row * CCH, l16); // self-loop
        float4 bv0 = ((const float4*)b0)[l16];
        float4 bv1 = ((const float4*)b1)[l16];
        bias = make_float4(bv0.x + bv1.x, bv0.y + bv1.y,
                           bv0.z + bv1.z, bv0.w + bv1.w);
        op = out + (size_t)row * CCH;
    } else {                                // gal: 4 segments of one list
        int r = row - N;
        int bg = rst[2 * N + r], eg = ren[2 * N + r];
        int len = eg - bg;
        beg = bg + ((len * q) >> 2);
        end = bg + ((len * (q + 1)) >> 2);
        hcL = h16 + 2 * NC;
        sdL = sdat + 2 * (size_t)GAPE;
        ddL = dinv[2 * N + r];
        if (q == 0) acc = gat4p(hcL + (size_t)r * CCH, l16);
        bias = ((const float4*)b2)[l16];
        op = out + NC + (size_t)r * CCH;
    }

    int i = beg;
    for (; i + 7 < end; i += 8) {           // unpredicated steady state
        int4a q0 = *(const int4a*)(sdL + i);
        int4a q1 = *(const int4a*)(sdL + i + 4);
        float4 v0 = gat4p(hcL + (size_t)q0.x * CCH, l16);
        float4 v1 = gat4p(hcL + (size_t)q0.y * CCH, l16);
        float4 v2 = gat4p(hcL + (size_t)q0.z * CCH, l16);
        float4 v3 = gat4p(hcL + (size_t)q0.w * CCH, l16);
        float4 v4 = gat4p(hcL + (size_t)q1.x * CCH, l16);
        float4 v5 = gat4p(hcL + (size_t)q1.y * CCH, l16);
        float4 v6 = gat4p(hcL + (size_t)q1.z * CCH, l16);
        float4 v7 = gat4p(hcL + (size_t)q1.w * CCH, l16);
        acc4(acc, v0); acc4(acc, v1); acc4(acc, v2); acc4(acc, v3);
        acc4(acc, v4); acc4(acc, v5); acc4(acc, v6); acc4(acc, v7);
    }
    if (i < end) {                          // ONE masked 8-wide tail shot
        // over-read stays inside sdat's CAP slack / following ws arrays.
        int4a q0 = *(const int4a*)(sdL + i);
        int4a q1 = *(const int4a*)(sdL + i + 4);
        const __half* p0 = hcL + (size_t)q0.x * CCH;   // i < end: valid
        const __half* p1 = (i + 1 < end) ? hcL + (size_t)q0.y * CCH : zrow;
        const __half* p2 = (i + 2 < end) ? hcL + (size_t)q0.z * CCH : zrow;
        const __half* p3 = (i + 3 < end) ? hcL + (size_t)q0.w * CCH : zrow;
        const __half* p4 = (i + 4 < end) ? hcL + (size_t)q1.x * CCH : zrow;
        const __half* p5 = (i + 5 < end) ? hcL + (size_t)q1.y * CCH : zrow;
        const __half* p6 = (i + 6 < end) ? hcL + (size_t)q1.z * CCH : zrow;
        const __half* p7 = (i + 7 < end) ? hcL + (size_t)q1.w * CCH : zrow;
        float4 v0 = gat4p(p0, l16);
        float4 v1 = gat4p(p1, l16);
        float4 v2 = gat4p(p2, l16);
        float4 v3 = gat4p(p3, l16);
        float4 v4 = gat4p(p4, l16);
        float4 v5 = gat4p(p5, l16);
        float4 v6 = gat4p(p6, l16);
        float4 v7 = gat4p(p7, l16);
        acc4(acc, v0); acc4(acc, v1); acc4(acc, v2); acc4(acc, v3);
        acc4(acc, v4); acc4(acc, v5); acc4(acc, v6); acc4(acc, v7);
    }

    float4 t;
    t.x = acc.x * ddL; t.y = acc.y * ddL; t.z = acc.z * ddL; t.w = acc.w * ddL;
    t.x += __shfl_xor(t.x, 16, 64); t.y += __shfl_xor(t.y, 16, 64);
    t.z += __shfl_xor(t.z, 16, 64); t.w += __shfl_xor(t.w, 16, 64);
    t.x += __shfl_xor(t.x, 32, 64); t.y += __shfl_xor(t.y, 32, 64);
    t.z += __shfl_xor(t.z, 32, 64); t.w += __shfl_xor(t.w, 32, 64);
    if (lane < 16) {
        t.x += bias.x; t.y += bias.y; t.z += bias.z; t.w += bias.w;
        ((float4*)op)[l16] = t;
    }
}

static inline size_t align256(size_t x) { return (x + 255) & ~(size_t)255; }

extern "C" void kernel_launch(void* const* d_in, const int* in_sizes, int n_in,
                              void* d_out, int out_size, void* d_ws, size_t ws_size,
                              hipStream_t stream) {
    const float* x_star = (const float*)d_in[0];
    const float* x_gal  = (const float*)d_in[1];
    const int*   e_ssn  = (const int*)d_in[2];
    const int*   e_ssf  = (const int*)d_in[3];
    const int*   e_ggn  = (const int*)d_in[4];
    const float* W_ssn  = (const float*)d_in[5];
    const float* W_ssf  = (const float*)d_in[6];
    const float* W_ggn  = (const float*)d_in[7];
    const float* b_ssn  = (const float*)d_in[8];
    const float* b_ssf  = (const float*)d_in[9];
    const float* b_ggn  = (const float*)d_in[10];

    const int N  = in_sizes[0] / CCH;       // 50000
    const int E  = in_sizes[2] / 2;         // 1000000
    const size_t NC = (size_t)N * CCH;
    const int NB   = (N + BKT - 1) / BKT;   // 196 buckets per conv
    const int NBLK = (E + PCH - 1) / PCH;   // 123 partition chunks per conv
    const int GAPE = NB * CAP;              // gapped per-conv region (1.2M recs)

    // workspace layout (sdat followed by bucketcur/rst/ren: pull tail over-read safe)
    char* w = (char*)d_ws;
    __half*   h16    = (__half*)w;   w += align256((size_t)3 * NC * 2);
    float*    dinv   = (float*)w;    w += align256((size_t)3 * N * 4);
    unsigned* bdata  = (unsigned*)w; w += align256((size_t)3 * GAPE * 4);
    int*      sdat   = (int*)w;      w += align256((size_t)3 * GAPE * 4);
    int*      bucketcur = (int*)w;   w += align256((size_t)3 * NB * 4);
    int*      rst    = (int*)w;      w += align256((size_t)3 * N * 4);
    int*      ren    = (int*)w;      w += align256((size_t)3 * N * 4);
    __half*   zrow   = (__half*)w;   w += align256((size_t)CCH * 2);

    const int B = 256;

    hipMemsetAsync(bucketcur, 0, (size_t)3 * NB * 4, stream);
    k_part<<<dim3(NBLK, 3), B, 0, stream>>>(e_ssn, e_ssf, e_ggn,
                                            bucketcur, bdata, E, NB);
    k_sort<<<dim3(NB, 3), B, 0, stream>>>(bdata, bucketcur, sdat,
                                          rst, ren, dinv, zrow, N, NB);
    k_gemm_all<<<dim3((N + GR - 1) / GR, 2), B, 0, stream>>>(x_star, x_gal,
                                                             W_ssn, W_ssf, W_ggn,
                                                             dinv, h16, N);
    k_pull<<<(2 * N + 3) / 4, B, 0, stream>>>(rst, ren, sdat, h16, dinv, zrow,
                                              b_ssn, b_ssf, b_ggn,
                                              (float*)d_out, N, GAPE);
}